// Round 5
// baseline (491.839 us; speedup 1.0000x reference)
//
#include <hip/hip_runtime.h>
#include <hip/hip_bf16.h>
#include <stdint.h>

typedef __bf16 bf16x8 __attribute__((ext_vector_type(8)));
typedef float  f32x4  __attribute__((ext_vector_type(4)));

#define NSLOPE 0.01f

// problem dims
#define NB   32
#define CIN  128
#define HIN  130
#define WIN  130
#define KOUT 256
#define POUT 128
#define QOUT 128
#define HWIN (HIN*WIN)            // 16900
#define PQ   (POUT*QOUT)

// workspace: X' (NHWC bf16) then W'' (fragment-packed bf16)
#define XP_BYTES 138444800ull     // 32*130*130*128*2
#define WP_ELEMS (18*2*8*2*64*8)  // 294912 bf16 = 589824 B

// LDS: X slab only, 4 h-rows x 130 w x 64 ci = 520 rows x 128 B = 66560 B -> 2 blocks/CU
#define XS_BYTES 66560

#define SB0()    __builtin_amdgcn_sched_barrier(0)
#define VMW(n)   asm volatile("s_waitcnt vmcnt(" #n ")" ::: "memory")
#define LGKMW(n) asm volatile("s_waitcnt lgkmcnt(" #n ")" ::: "memory")

__device__ __forceinline__ unsigned short f2bf(float f) {
    unsigned u = __builtin_bit_cast(unsigned, f);
    u += 0x7FFFu + ((u >> 16) & 1u);   // RNE
    return (unsigned short)(u >> 16);
}

__device__ __forceinline__ void g2lds16(const void* g, void* l) {
    __builtin_amdgcn_global_load_lds(
        (const __attribute__((address_space(1))) void*)g,
        (__attribute__((address_space(3))) void*)l,
        16, 0, 0);
}

// ---------------- pre-pass 1: X NCHW fp32 -> NHWC bf16 ----------------
__global__ __launch_bounds__(256) void k_conv_x(const float* __restrict__ X,
                                                unsigned short* __restrict__ Xp) {
    __shared__ unsigned short tile[130*132];   // [w][c], c padded 128->132
    const int b = blockIdx.x;                  // n*130 + h
    const int n = b / 130, h = b - n*130;
    const int tid = threadIdx.x;
    const size_t in_base = (size_t)n*(CIN*(size_t)HWIN) + (size_t)h*WIN;
    for (int fi = tid; fi < CIN*WIN; fi += 256) {
        int c = fi / WIN, w = fi - c*WIN;
        tile[w*132 + c] = f2bf(X[in_base + (size_t)c*HWIN + w]);
    }
    __syncthreads();
    unsigned short* outp = Xp + (size_t)b * (WIN*CIN);
    for (int oi = tid; oi < (WIN*CIN)/4; oi += 256) {
        int e = oi*4; int w = e >> 7; int c4 = e & 127;
        const unsigned short* t = &tile[w*132 + c4];
        ushort4 v; v.x = t[0]; v.y = t[1]; v.z = t[2]; v.w = t[3];
        *(ushort4*)(outp + e) = v;
    }
}

// ---------------- pre-pass 2: W OIHW fp32 -> W'' fragment-packed ----------------
// element e: j=e&7, lane=(e>>3)&63, kq=(e>>9)&1, fr=(e>>10)&7, kh=(e>>13)&1, rsidx=e>>14
// value = W[kout = kh*128+fr*16+(lane&15)][ci = cc*64+kq*32+(lane>>4)*8+j][rr][s]
__global__ __launch_bounds__(256) void k_conv_w(const float* __restrict__ W,
                                                unsigned short* __restrict__ Wp) {
    int e = blockIdx.x*256 + threadIdx.x;
    if (e >= WP_ELEMS) return;
    int j     = e & 7;
    int lane  = (e >> 3) & 63;
    int kq    = (e >> 9) & 1;
    int fr    = (e >> 10) & 7;
    int kh    = (e >> 13) & 1;
    int rsidx = e >> 14;                       // 0..17
    int cc = rsidx / 9; int rem = rsidx - cc*9; int rr = rem / 3, s = rem - rr*3;
    int kout = kh*128 + fr*16 + (lane & 15);
    int ci   = cc*64 + kq*32 + (lane >> 4)*8 + j;
    Wp[e] = f2bf(W[(size_t)kout*1152 + (size_t)ci*9 + rr*3 + s]);
}

// ---------------- X slab staging: linear LDS dest, inverse-swizzled global src ----------------
// swizzle: phys = logical ^ ((row&7)<<4), row = phys>>7 (128 B rows)
__device__ __forceinline__ void stage_x4(const unsigned short* __restrict__ Xp,
                                         unsigned char* lds, int n, int p2, int cc, int tid) {
    #pragma unroll
    for (int it = 0; it < 17; ++it) {
        const int t = it*256 + tid;
        if (t < 4160) {
            const int phys = t << 4;
            const int g    = phys >> 7;                  // rloc*130 + w, 0..519
            const int rloc = g / 130;
            const int w    = g - 130*rloc;
            const int cib  = (phys & 127) ^ ((g & 7) << 4);
            const unsigned short* src =
                Xp + ((size_t)((n*HIN + p2 + rloc)*WIN + w))*CIN + cc*64 + (cib >> 1);
            g2lds16(src, lds + phys);
        }
    }
}

// ---------------- main conv: 128 kout x 256 pq tile, 4 waves, barrier-free K-loop ----------------
// A (W'') direct global->VGPR from L2; B (X) via LDS slab; 16x16x32 MFMA.
#define ISSUE_A(A_, rsidx, kq) do {                                               \
    const unsigned char* ab_ = wfp + (size_t)(rsidx)*32768 + khOff + wmOff        \
                               + (kq)*1024 + laneB;                               \
    A_[0] = *(const bf16x8*)(ab_);                                                \
    A_[1] = *(const bf16x8*)(ab_ + 2048);                                         \
    A_[2] = *(const bf16x8*)(ab_ + 4096);                                         \
    A_[3] = *(const bf16x8*)(ab_ + 6144);                                         \
} while (0)

#define ISSUE_B(B_, stv, kq) do {                                                 \
    const int rr_ = (stv) / 3, ss_ = (stv) - rr_*3;                               \
    const int g0_ = (wn + rr_)*130 + l15 + ss_;                                   \
    const int gb_ = g0_*128 + (((kq)*64 + kg16) ^ ((g0_ & 7) << 4));              \
    _Pragma("unroll")                                                             \
    for (int nf = 0; nf < 8; ++nf)                                                \
        B_[nf] = *(const bf16x8*)(xs + gb_ + nf*2048);                            \
} while (0)

#define MMA(A_, B_) do {                                                          \
    __builtin_amdgcn_s_setprio(1);                                                \
    _Pragma("unroll")                                                             \
    for (int mf = 0; mf < 4; ++mf)                                                \
        _Pragma("unroll")                                                         \
        for (int nf = 0; nf < 8; ++nf)                                            \
            acc[mf][nf] = __builtin_amdgcn_mfma_f32_16x16x32_bf16(                \
                A_[mf], B_[nf], acc[mf][nf], 0, 0, 0);                            \
    __builtin_amdgcn_s_setprio(0);                                                \
} while (0)

__global__ __launch_bounds__(256, 2) void k_conv_main(
    const unsigned short* __restrict__ Xp,
    const unsigned short* __restrict__ Wpp,
    const float* __restrict__ bias,
    float* __restrict__ out)
{
    extern __shared__ __align__(16) unsigned char xs[];

    const int tid  = threadIdx.x;
    const int lane = tid & 63;
    const int wid  = tid >> 6;
    const int wm   = wid >> 1;         // kout 64-block within the 128-half
    const int wn   = wid & 1;          // p-row within the 2-row pq tile
    const int l15  = lane & 15;
    const int kg   = lane >> 4;
    const int kg16 = kg << 4;
    const int laneB = lane << 4;

    // bijective XCD swizzle (4096 = 8 x 512); kh pairs stay on one XCD
    const int L   = ((blockIdx.x & 7) << 9) | (blockIdx.x >> 3);
    const int kh  = L & 1;
    const int pqt = L >> 1;            // 0..2047
    const int n   = pqt >> 6;
    const int p2  = (pqt & 63) << 1;

    const unsigned char* wfp = (const unsigned char*)Wpp;
    const int khOff = kh << 14;        // kh*16384
    const int wmOff = wm << 13;        // wm*8192

    f32x4 acc[4][8];
    #pragma unroll
    for (int i = 0; i < 4; ++i)
        #pragma unroll
        for (int j = 0; j < 8; ++j)
            acc[i][j] = (f32x4){0.f, 0.f, 0.f, 0.f};

    bf16x8 A0[4], A1[4], B0[8], B1[8];

    stage_x4(Xp, xs, n, p2, 0, tid);
    VMW(0);
    __builtin_amdgcn_s_barrier();

    #pragma unroll 1
    for (int cc = 0; cc < 2; ++cc) {
        const int rsb = cc*9;

        // prologue: issue units (st=0,kq=0) and (st=0,kq=1)
        ISSUE_A(A0, rsb, 0); ISSUE_B(B0, 0, 0); SB0();
        ISSUE_A(A1, rsb, 1); ISSUE_B(B1, 0, 1); SB0();

        #pragma unroll 1
        for (int st = 0; st < 9; ++st) {
            // consume set0 (A done when only set1's 4 loads outstanding)
            VMW(4); LGKMW(8); SB0();
            MMA(A0, B0); SB0();
            if (st < 8) { ISSUE_A(A0, rsb + st + 1, 0); ISSUE_B(B0, st + 1, 0); }
            SB0();
            // consume set1
            if (st < 8) { VMW(4); LGKMW(8); } else { VMW(0); LGKMW(0); }
            SB0();
            MMA(A1, B1); SB0();
            if (st < 8) { ISSUE_A(A1, rsb + st + 1, 1); ISSUE_B(B1, st + 1, 1); }
            SB0();
        }

        if (cc == 0) {   // restage X slab for ci half 1
            __builtin_amdgcn_s_barrier();
            stage_x4(Xp, xs, n, p2, 1, tid);
            VMW(0);
            __builtin_amdgcn_s_barrier();
        }
    }

    // epilogue: D col(q) = lane&15, row(kout) = kg*4 + j -> coalesced 64-B segments
    #pragma unroll
    for (int mf = 0; mf < 4; ++mf) {
        const int kb = kh*128 + wm*64 + mf*16 + kg*4;
        const float4 bv = *(const float4*)(bias + kb);
        const float bj[4] = {bv.x, bv.y, bv.z, bv.w};
        #pragma unroll
        for (int nf = 0; nf < 8; ++nf) {
            const int q = nf*16 + l15;
            const size_t base = (((size_t)n*KOUT + kb)*POUT + (p2 + wn))*QOUT + q;
            #pragma unroll
            for (int j = 0; j < 4; ++j) {
                float y = (acc[mf][nf][j] + bj[j]) * 0.5f;
                out[base + (size_t)j*PQ] = (y >= 0.f) ? y : y*NSLOPE;
            }
        }
    }
}

extern "C" void kernel_launch(void* const* d_in, const int* in_sizes, int n_in,
                              void* d_out, int out_size, void* d_ws, size_t ws_size,
                              hipStream_t stream) {
    const float* X = (const float*)d_in[0];
    const float* W = (const float*)d_in[1];
    const float* B = (const float*)d_in[2];
    float* out = (float*)d_out;
    unsigned short* Xp = (unsigned short*)d_ws;
    unsigned short* Wp = (unsigned short*)((char*)d_ws + XP_BYTES);

    (void)hipFuncSetAttribute((const void*)k_conv_main,
                              hipFuncAttributeMaxDynamicSharedMemorySize, XS_BYTES);

    k_conv_x   <<<NB*HIN, 256, 0, stream>>>(X, Xp);
    k_conv_w   <<<(WP_ELEMS + 255)/256, 256, 0, stream>>>(W, Wp);
    k_conv_main<<<4096, 256, XS_BYTES, stream>>>(Xp, Wp, B, out);
}

// Round 6
// 425.673 us; speedup vs baseline: 1.1554x; 1.1554x over previous
//
#include <hip/hip_runtime.h>
#include <hip/hip_bf16.h>
#include <stdint.h>

typedef __bf16 bf16x8 __attribute__((ext_vector_type(8)));
typedef float  f32x4  __attribute__((ext_vector_type(4)));
typedef unsigned short ushort8v __attribute__((ext_vector_type(8)));

#define NSLOPE 0.01f

// problem dims
#define NB   32
#define CIN  128
#define HIN  130
#define WIN  130
#define KOUT 256
#define POUT 128
#define QOUT 128
#define HWIN (HIN*WIN)            // 16900
#define PQ   (POUT*QOUT)

// workspace: X' (NHWC bf16) then W' ([rsidx][k 256][ci 64] bf16)
#define XP_BYTES 138444800ull     // 32*130*130*128*2
#define WP_ELEMS (2*3*3*KOUT*64)  // 294912

// LDS: W tile [128 kout][64 ci] = 16384 B @0 ; X tile [130 w][64 ci] = 16640 B @16384
// 33024 B total -> 4 blocks/CU
#define XT_OFF    16384
#define LDS_TOTAL (16384 + 16640)

__device__ __forceinline__ unsigned short f2bf(float f) {
    unsigned u = __builtin_bit_cast(unsigned, f);
    u += 0x7FFFu + ((u >> 16) & 1u);   // RNE
    return (unsigned short)(u >> 16);
}

__device__ __forceinline__ void g2lds16(const void* g, void* l) {
    __builtin_amdgcn_global_load_lds(
        (const __attribute__((address_space(1))) void*)g,
        (__attribute__((address_space(3))) void*)l,
        16, 0, 0);
}

// ---------------- pre-pass 1: X NCHW fp32 -> NHWC bf16 (vectorized) ----------------
__global__ __launch_bounds__(256) void k_conv_x(const float* __restrict__ X,
                                                unsigned short* __restrict__ Xp) {
    __shared__ unsigned short tile[130*132];   // [w][c], c padded 128->132
    const int b = blockIdx.x;                  // n*130 + h
    const int n = b / 130, h = b - n*130;
    const int tid = threadIdx.x;
    const size_t in_base = (size_t)n*(CIN*(size_t)HWIN) + (size_t)h*WIN;
    // 65 float2 per (c,row): 8320 chunks
    for (int fi = tid; fi < CIN*65; fi += 256) {
        int c = fi / 65, w2 = fi - c*65;
        float2 v = *(const float2*)(X + in_base + (size_t)c*HWIN + w2*2);
        tile[(w2*2  )*132 + c] = f2bf(v.x);
        tile[(w2*2+1)*132 + c] = f2bf(v.y);
    }
    __syncthreads();
    unsigned short* outp = Xp + (size_t)b * (WIN*CIN);
    // 2080 ushort8 chunks
    for (int oi = tid; oi < (WIN*CIN)/8; oi += 256) {
        int e = oi*8; int w = e >> 7; int c8 = e & 127;
        const unsigned short* t = &tile[w*132 + c8];
        ushort8v v;
        #pragma unroll
        for (int j = 0; j < 8; ++j) v[j] = t[j];
        *(ushort8v*)(outp + e) = v;
    }
}

// ---------------- pre-pass 2: W OIHW fp32 -> W' [rsidx][k][ci] bf16 ----------------
__global__ __launch_bounds__(256) void k_conv_w(const float* __restrict__ W,
                                                unsigned short* __restrict__ Wp) {
    int e = blockIdx.x*256 + threadIdx.x;
    if (e >= WP_ELEMS) return;
    int ci = e & 63;
    int k  = (e >> 6) & 255;
    int rsIdx = e >> 14;                       // 0..17 = cc*9 + r*3 + s
    int cc = rsIdx / 9; int rem = rsIdx - cc*9; int r = rem / 3, s = rem - r*3;
    int c = cc*64 + ci;
    Wp[e] = f2bf(W[(size_t)k*1152 + (size_t)c*9 + r*3 + s]);
}

// ---------------- main conv: 128 kout x 128 q, 2 waves of 64x128, 4 blocks/CU ----------------
// swizzle: phys = logical ^ ((row&7)<<4), rows are 128 B
__global__ __launch_bounds__(128, 2) void k_conv_main(
    const unsigned short* __restrict__ Xp,
    const unsigned short* __restrict__ Wp,
    const float* __restrict__ bias,
    float* __restrict__ out)
{
    __shared__ __align__(16) unsigned char smem[LDS_TOTAL];

    const int tid  = threadIdx.x;
    const int lane = tid & 63;
    const int wm   = tid >> 6;        // 0..1: kout 64-block within the kh-half
    const int l15  = lane & 15;
    const int kg16 = (lane >> 4) << 4;

    // grid 8192 = 8 XCD-chunks x 1024; L = n*256 + p*2 + kh (kh pairs adjacent, same XCD)
    const int L  = ((blockIdx.x & 7) << 10) | (blockIdx.x >> 3);
    const int kh = L & 1;
    const int np = L >> 1;
    const int p  = np & 127;
    const int n  = np >> 7;

    f32x4 acc[4][8];
    #pragma unroll
    for (int i = 0; i < 4; ++i)
        #pragma unroll
        for (int j = 0; j < 8; ++j)
            acc[i][j] = (f32x4){0.f, 0.f, 0.f, 0.f};

    #pragma unroll 1
    for (int t = 0; t < 18; ++t) {
        const int cc = t / 9;
        const int rem = t - cc*9;
        const int r  = rem / 3;
        const int s  = rem - r*3;

        __syncthreads();   // all reads of both tiles from previous step complete

        // stage W(cc,r,s): 1024 granules over 128 threads
        {
            const unsigned short* wbase = Wp + (size_t)t*(KOUT*64) + (size_t)(kh*128)*64;
            #pragma unroll
            for (int it = 0; it < 8; ++it) {
                const int g    = it*128 + tid;
                const int phys = g << 4;
                const int row  = phys >> 7;                      // kout-local 0..127
                const int cib  = (phys & 127) ^ ((row & 7) << 4);
                g2lds16(wbase + (size_t)row*64 + (cib >> 1), smem + phys);
            }
        }
        // stage X(cc, p+r): 1040 granules (only when r advances)
        if (s == 0) {
            const unsigned short* xbase =
                Xp + ((size_t)((n*HIN + (p + r))*WIN))*CIN + cc*64;
            #pragma unroll
            for (int it = 0; it < 9; ++it) {
                const int g = it*128 + tid;
                if (g < 1040) {
                    const int phys = g << 4;
                    const int w    = phys >> 7;                  // 0..129
                    const int cib  = (phys & 127) ^ ((w & 7) << 4);
                    g2lds16(xbase + (size_t)w*CIN + (cib >> 1), smem + XT_OFF + phys);
                }
            }
        }

        __syncthreads();   // drains vmcnt: tiles ready

        #pragma unroll
        for (int kq = 0; kq < 2; ++kq) {
            const int cib0 = kq*64 + kg16;
            bf16x8 A[4], B[8];
            #pragma unroll
            for (int mf = 0; mf < 4; ++mf) {
                const int row = wm*64 + mf*16 + l15;
                A[mf] = *(const bf16x8*)(smem + row*128 + (cib0 ^ ((row & 7) << 4)));
            }
            #pragma unroll
            for (int nf = 0; nf < 8; ++nf) {
                const int g = nf*16 + l15 + s;                   // w = q + s
                B[nf] = *(const bf16x8*)(smem + XT_OFF + g*128 + (cib0 ^ ((g & 7) << 4)));
            }
            #pragma unroll
            for (int mf = 0; mf < 4; ++mf)
                #pragma unroll
                for (int nf = 0; nf < 8; ++nf)
                    acc[mf][nf] = __builtin_amdgcn_mfma_f32_16x16x32_bf16(
                        A[mf], B[nf], acc[mf][nf], 0, 0, 0);
        }
    }

    // epilogue: D col(q) = lane&15, row(kout) = kg*4 + j -> coalesced 64-B segments
    const int kg = lane >> 4;
    #pragma unroll
    for (int mf = 0; mf < 4; ++mf) {
        const int kb = kh*128 + wm*64 + mf*16 + kg*4;
        const float4 bv = *(const float4*)(bias + kb);
        const float bj[4] = {bv.x, bv.y, bv.z, bv.w};
        #pragma unroll
        for (int nf = 0; nf < 8; ++nf) {
            const int q = nf*16 + l15;
            const size_t base = (((size_t)n*KOUT + kb)*POUT + p)*QOUT + q;
            #pragma unroll
            for (int j = 0; j < 4; ++j) {
                float y = (acc[mf][nf][j] + bj[j]) * 0.5f;
                out[base + (size_t)j*PQ] = (y >= 0.f) ? y : y*NSLOPE;
            }
        }
    }
}

extern "C" void kernel_launch(void* const* d_in, const int* in_sizes, int n_in,
                              void* d_out, int out_size, void* d_ws, size_t ws_size,
                              hipStream_t stream) {
    const float* X = (const float*)d_in[0];
    const float* W = (const float*)d_in[1];
    const float* B = (const float*)d_in[2];
    float* out = (float*)d_out;
    unsigned short* Xp = (unsigned short*)d_ws;
    unsigned short* Wp = (unsigned short*)((char*)d_ws + XP_BYTES);

    k_conv_x   <<<NB*HIN, 256, 0, stream>>>(X, Xp);
    k_conv_w   <<<(WP_ELEMS + 255)/256, 256, 0, stream>>>(W, Wp);
    k_conv_main<<<8192, 128, 0, stream>>>(Xp, Wp, B, out);
}